// Round 11
// baseline (301.554 us; speedup 1.0000x reference)
//
#include <hip/hip_runtime.h>
#include <math.h>

#define N_NODES 50000
#define E_EDGES 800000
#define D_DIM   128
#define H_HEADS 8
#define DH_DIM  16
#define DFF     512

#define SCAN_BLOCKS 98  // 98*512 = 50176 >= N_NODES+1

typedef __bf16 bf16_t;
typedef bf16_t bf16x8 __attribute__((ext_vector_type(8)));
typedef float f32x4 __attribute__((ext_vector_type(4)));
typedef unsigned short u16x8 __attribute__((ext_vector_type(8)));

#define SWZ(r) (((r) & 7) << 4)

__device__ __forceinline__ float lrelu(float v) { return v > 0.f ? v : 0.01f * v; }
__device__ __forceinline__ float elu(float v) { return v > 0.f ? v : __expf(v) - 1.f; }
__device__ __forceinline__ unsigned short f2b(float f) {
    unsigned u = __float_as_uint(f);
    unsigned r = (u + 0x7FFFu + ((u >> 16) & 1u)) >> 16;
    return (unsigned short)r;
}

// ---------------- zero counts ----------------
__global__ void k_zero(int* __restrict__ counts) {
    int i = blockIdx.x * 256 + threadIdx.x;
    if (i < N_NODES) counts[i] = 0;
}

// ---------------- count in-degree ----------------
__global__ void k_count(const int* __restrict__ ed, int* __restrict__ counts) {
    int e = blockIdx.x * 256 + threadIdx.x;
    if (e < E_EDGES) atomicAdd(&counts[ed[e]], 1);
}

// ---------------- hierarchical scan ----------------
__global__ __launch_bounds__(512) void k_scan1(const int* __restrict__ counts,
                                               int* __restrict__ bsum) {
    int i = blockIdx.x * 512 + threadIdx.x;
    int v = (i < N_NODES) ? counts[i] : 0;
    #pragma unroll
    for (int o = 1; o < 64; o <<= 1) v += __shfl_xor(v, o);
    __shared__ int ws[8];
    if ((threadIdx.x & 63) == 0) ws[threadIdx.x >> 6] = v;
    __syncthreads();
    if (threadIdx.x == 0) {
        int s = 0;
        #pragma unroll
        for (int k = 0; k < 8; ++k) s += ws[k];
        bsum[blockIdx.x] = s;
    }
}

__global__ __launch_bounds__(128) void k_scan2(const int* __restrict__ bsum,
                                               int* __restrict__ boff) {
    __shared__ int tmp[128];
    int t = threadIdx.x;
    int v = (t < SCAN_BLOCKS) ? bsum[t] : 0;
    tmp[t] = v;
    __syncthreads();
    for (int o = 1; o < 128; o <<= 1) {
        int u = (t >= o) ? tmp[t - o] : 0;
        __syncthreads();
        tmp[t] += u;
        __syncthreads();
    }
    boff[t] = (t == 0) ? 0 : tmp[t - 1];
}

__global__ __launch_bounds__(512) void k_scan3(const int* __restrict__ counts,
                                               const int* __restrict__ boff,
                                               int* __restrict__ csr_off,
                                               int* __restrict__ cursor) {
    int t = threadIdx.x;
    int i = blockIdx.x * 512 + t;
    int v = (i < N_NODES) ? counts[i] : 0;
    int lane = t & 63, w = t >> 6;
    int xs = v;
    #pragma unroll
    for (int o = 1; o < 64; o <<= 1) {
        int u = __shfl_up(xs, o);
        if (lane >= o) xs += u;
    }
    __shared__ int ws[8];
    __shared__ int wo[8];
    if (lane == 63) ws[w] = xs;
    __syncthreads();
    if (t == 0) {
        int s = 0;
        #pragma unroll
        for (int k = 0; k < 8; ++k) { wo[k] = s; s += ws[k]; }
    }
    __syncthreads();
    int excl = xs - v + wo[w] + boff[blockIdx.x];
    if (i < N_NODES) { csr_off[i] = excl; cursor[i] = excl; }
    if (i == N_NODES) csr_off[N_NODES] = E_EDGES;
}

// ---------------- fill CSR with src ids ----------------
__global__ void k_fill(const int* __restrict__ es, const int* __restrict__ ed,
                       int* __restrict__ cursor, int* __restrict__ csr_src) {
    int e = blockIdx.x * 256 + threadIdx.x;
    if (e < E_EDGES) {
        int pos = atomicAdd(&cursor[ed[e]], 1);
        csr_src[pos] = es[e];
    }
}

// ---------------- weight prep: transpose + bf16 ----------------
__global__ void k_prep(const float* __restrict__ W1, const float* __restrict__ W2,
                       const float* __restrict__ Wfc,
                       bf16_t* __restrict__ W1T, bf16_t* __restrict__ W2T,
                       bf16_t* __restrict__ WpT) {
    int id = blockIdx.x * 256 + threadIdx.x;
    if (id < 512 * 128) {
        int c = id >> 7, k = id & 127;
        W1T[id] = (bf16_t)W1[(size_t)k * 512 + c];
        int c2 = id >> 9, k2 = id & 511;
        W2T[id] = (bf16_t)W2[(size_t)k2 * 128 + c2];
        if (id < 128 * 128) {
            int cp = id >> 7, kp = id & 127;
            WpT[id] = (bf16_t)Wfc[(cp >> 4) * 2048 + kp * 16 + (cp & 15)];
        }
    }
}

// ---------------- z = x @ Wp via bf16 MFMA + fused el/er + zb ----------------
__global__ __launch_bounds__(512) void k_proj(const float* __restrict__ x,
                                              const bf16_t* __restrict__ WpT,
                                              const float* __restrict__ a_l,
                                              const float* __restrict__ a_r,
                                              unsigned short* __restrict__ zb,
                                              float* __restrict__ el,
                                              float* __restrict__ er) {
    __shared__ char xbA[16384];  // bf16[64][128], row stride 256B, swizzled
    int t = threadIdx.x;
    int r0 = blockIdx.x * 64;

    {
        int r = t >> 3, c0 = (t & 7) * 16;
        int gr = r0 + r;
        u16x8 pk0, pk1;
        if (gr < N_NODES) {
            #pragma unroll
            for (int q = 0; q < 2; ++q) {
                float4 a4 = *(const float4*)&x[(size_t)gr * 128 + c0 + q * 8];
                float4 b4 = *(const float4*)&x[(size_t)gr * 128 + c0 + q * 8 + 4];
                u16x8 pk;
                pk[0] = f2b(a4.x); pk[1] = f2b(a4.y); pk[2] = f2b(a4.z); pk[3] = f2b(a4.w);
                pk[4] = f2b(b4.x); pk[5] = f2b(b4.y); pk[6] = f2b(b4.z); pk[7] = f2b(b4.w);
                if (q == 0) pk0 = pk; else pk1 = pk;
            }
        } else {
            #pragma unroll
            for (int i = 0; i < 8; ++i) { pk0[i] = 0; pk1[i] = 0; }
        }
        int base = r * 256 + c0 * 2;
        *(u16x8*)(xbA + (base ^ SWZ(r))) = pk0;
        *(u16x8*)(xbA + ((base + 16) ^ SWZ(r))) = pk1;
    }
    __syncthreads();

    int wv = t >> 6, l = t & 63;
    int lr = l & 15, lg = l >> 4;

    f32x4 acc[4] = {};
    #pragma unroll
    for (int ks = 0; ks < 4; ++ks) {
        bf16x8 b = *(const bf16x8*)(WpT + (wv * 16 + lr) * 128 + ks * 32 + lg * 8);
        #pragma unroll
        for (int mi = 0; mi < 4; ++mi) {
            int row = mi * 16 + lr;
            int off = (row * 256 + ks * 64 + lg * 16) ^ SWZ(row);
            bf16x8 a = *(const bf16x8*)(xbA + off);
            acc[mi] = __builtin_amdgcn_mfma_f32_16x16x32_bf16(a, b, acc[mi], 0, 0, 0);
        }
    }

    float alv = a_l[wv * 16 + lr];
    float arv = a_r[wv * 16 + lr];
    float outL = 0.f, outR = 0.f;
    #pragma unroll
    for (int mi = 0; mi < 4; ++mi) {
        #pragma unroll
        for (int rg = 0; rg < 4; ++rg) {
            int row = mi * 16 + lg * 4 + rg;
            int grr = r0 + row;
            float v = acc[mi][rg];
            if (grr < N_NODES) zb[(size_t)grr * 128 + wv * 16 + lr] = f2b(v);
            float pl = v * alv, pr = v * arv;
            pl += __shfl_xor(pl, 1); pr += __shfl_xor(pr, 1);
            pl += __shfl_xor(pl, 2); pr += __shfl_xor(pr, 2);
            pl += __shfl_xor(pl, 4); pr += __shfl_xor(pr, 4);
            pl += __shfl_xor(pl, 8); pr += __shfl_xor(pr, 8);
            if (lr == mi * 4 + rg) { outL = pl; outR = pr; }
        }
    }
    int myrow = r0 + (lr >> 2) * 16 + lg * 4 + (lr & 3);
    if (myrow < N_NODES) {
        el[myrow * 8 + wv] = outL;
        er[myrow * 8 + wv] = outR;
    }
}

// ---------------- fused softmax + aggregate + elu + residual ----------------
// TWO nodes per wave (one per half-wave): 2 independent dep chains, 8B gathers.
__global__ __launch_bounds__(256) void k_node(const int* __restrict__ csr_off,
                                              const int* __restrict__ csr_src,
                                              const float* __restrict__ el,
                                              const float* __restrict__ er,
                                              const unsigned short* __restrict__ zb,
                                              const float* __restrict__ x,
                                              float* __restrict__ out) {
    int n = blockIdx.x * 8 + (threadIdx.x >> 5);
    int lane = threadIdx.x & 63;
    int q = lane & 31;
    int base = lane & 32;       // shuffle base of this half-wave
    int h = q >> 2, s = q & 3;
    int row = csr_off[n];
    int deg = csr_off[n + 1] - row;
    float4 xv = *(const float4*)&x[(size_t)n * 128 + q * 4];
    float erv = er[n * 8 + h];
    int nch = (deg + 3) >> 2;

    float ev[8];
    int srcv[8];
    float mx = -INFINITY;
    #pragma unroll
    for (int c = 0; c < 8; ++c) {
        int k = c * 4 + s;
        int src = 0;
        float e = -INFINITY;
        if (c * 4 < deg) {  // uniform across half-wave
            if (k < deg) {
                src = csr_src[row + k];
                e = lrelu(el[src * 8 + h] + erv);
            }
        }
        ev[c] = e;
        srcv[c] = src;
        mx = fmaxf(mx, e);
    }
    for (int c = 8; c < nch; ++c) {  // rare: deg > 32
        int k = c * 4 + s;
        if (k < deg) {
            int src = csr_src[row + k];
            mx = fmaxf(mx, lrelu(el[src * 8 + h] + erv));
        }
    }
    mx = fmaxf(mx, __shfl_xor(mx, 1));
    mx = fmaxf(mx, __shfl_xor(mx, 2));

    float ps = 0.f;
    float ac0 = 0.f, ac1 = 0.f, ac2 = 0.f, ac3 = 0.f;
    const unsigned short* zbl = zb + q * 4;
    #pragma unroll
    for (int c = 0; c < 8; ++c) {
        if (c * 4 < deg) {  // uniform across half-wave
            float p = ((c * 4 + s) < deg) ? __expf(ev[c] - mx) : 0.f;
            ps += p;
            float a[4];
            int se[4];
            #pragma unroll
            for (int tt = 0; tt < 4; ++tt) {
                a[tt] = __shfl(p, base + h * 4 + tt);
                se[tt] = __shfl(srcv[c], base + tt);
            }
            uint2 u[4];
            #pragma unroll
            for (int tt = 0; tt < 4; ++tt)
                u[tt] = *(const uint2*)(zbl + (size_t)se[tt] * 128);
            #pragma unroll
            for (int tt = 0; tt < 4; ++tt) {
                ac0 += a[tt] * __uint_as_float(u[tt].x << 16);
                ac1 += a[tt] * __uint_as_float(u[tt].x & 0xFFFF0000u);
                ac2 += a[tt] * __uint_as_float(u[tt].y << 16);
                ac3 += a[tt] * __uint_as_float(u[tt].y & 0xFFFF0000u);
            }
        }
    }
    for (int c = 8; c < nch; ++c) {  // rare: deg > 32
        int k = c * 4 + s;
        int src = 0;
        float e = -INFINITY;
        if (k < deg) {
            src = csr_src[row + k];
            e = lrelu(el[src * 8 + h] + erv);
        }
        float p = (k < deg) ? __expf(e - mx) : 0.f;
        ps += p;
        float a[4];
        int se[4];
        #pragma unroll
        for (int tt = 0; tt < 4; ++tt) {
            a[tt] = __shfl(p, base + h * 4 + tt);
            se[tt] = __shfl(src, base + tt);
        }
        uint2 u[4];
        #pragma unroll
        for (int tt = 0; tt < 4; ++tt)
            u[tt] = *(const uint2*)(zbl + (size_t)se[tt] * 128);
        #pragma unroll
        for (int tt = 0; tt < 4; ++tt) {
            ac0 += a[tt] * __uint_as_float(u[tt].x << 16);
            ac1 += a[tt] * __uint_as_float(u[tt].x & 0xFFFF0000u);
            ac2 += a[tt] * __uint_as_float(u[tt].y << 16);
            ac3 += a[tt] * __uint_as_float(u[tt].y & 0xFFFF0000u);
        }
    }
    ps += __shfl_xor(ps, 1);
    ps += __shfl_xor(ps, 2);
    float inv = 1.f / fmaxf(ps, 1e-9f);
    float4 hv;
    hv.x = xv.x + elu(ac0 * inv);
    hv.y = xv.y + elu(ac1 * inv);
    hv.z = xv.z + elu(ac2 * inv);
    hv.w = xv.w + elu(ac3 * inv);
    *(float4*)&out[(size_t)n * 128 + q * 4] = hv;
}

// ---------------- fused LN+FFN, BARRIER-FREE (swapped-operand MFMA) ---------
// Each wave owns 16 nodes end-to-end; zero __syncthreads. GEMM1 computes
// inter^T = W1T . ln^T (ln^T B-frags built in registers at LN time); inter^T
// transits a wave-private 4KB LDS quarter buffer (same-wave ds ordering, no
// barrier); GEMM2 computes out2^T = W2T . inter^T. Epilogue float4 RMW.
__global__ __launch_bounds__(256) void k_ffn(const float* __restrict__ gamma,
                                             const float* __restrict__ beta,
                                             const bf16_t* __restrict__ W1T,
                                             const float* __restrict__ b1,
                                             const bf16_t* __restrict__ W2T,
                                             const float* __restrict__ b2,
                                             float* __restrict__ out) {
    __shared__ char smem[32768];  // 4 waves x 2 ping-pong x 4KB
    int t = threadIdx.x;
    int wv = t >> 6, l = t & 63;
    int lr = l & 15, lg = l >> 4;
    char* lds0 = smem + wv * 8192;
    int node = blockIdx.x * 64 + wv * 16 + lr;
    bool ok = node < N_NODES;
    const float* hrow = out + (size_t)node * 128;

    // phase 0: load h row-fragments (node=lr, k-slice by lg), LN, pack ln^T
    float hv[4][8];
    #pragma unroll
    for (int ks = 0; ks < 4; ++ks) {
        float4 a4 = make_float4(0.f, 0.f, 0.f, 0.f), c4 = a4;
        if (ok) {
            a4 = *(const float4*)(hrow + ks * 32 + lg * 8);
            c4 = *(const float4*)(hrow + ks * 32 + lg * 8 + 4);
        }
        hv[ks][0] = a4.x; hv[ks][1] = a4.y; hv[ks][2] = a4.z; hv[ks][3] = a4.w;
        hv[ks][4] = c4.x; hv[ks][5] = c4.y; hv[ks][6] = c4.z; hv[ks][7] = c4.w;
    }
    float sm = 0.f, sq = 0.f;
    #pragma unroll
    for (int ks = 0; ks < 4; ++ks)
        #pragma unroll
        for (int j = 0; j < 8; ++j) { float v = hv[ks][j]; sm += v; sq += v * v; }
    sm += __shfl_xor(sm, 16); sq += __shfl_xor(sq, 16);
    sm += __shfl_xor(sm, 32); sq += __shfl_xor(sq, 32);
    float mu = sm * (1.f / 128.f);
    float rs = rsqrtf(sq * (1.f / 128.f) - mu * mu + 1e-5f);
    bf16x8 lnb[4];
    #pragma unroll
    for (int ks = 0; ks < 4; ++ks) {
        float4 g0 = *(const float4*)&gamma[ks * 32 + lg * 8];
        float4 g1 = *(const float4*)&gamma[ks * 32 + lg * 8 + 4];
        float4 be0 = *(const float4*)&beta[ks * 32 + lg * 8];
        float4 be1 = *(const float4*)&beta[ks * 32 + lg * 8 + 4];
        float ga[8] = {g0.x, g0.y, g0.z, g0.w, g1.x, g1.y, g1.z, g1.w};
        float ba[8] = {be0.x, be0.y, be0.z, be0.w, be1.x, be1.y, be1.z, be1.w};
        u16x8 pk;
        #pragma unroll
        for (int j = 0; j < 8; ++j)
            pk[j] = f2b((hv[ks][j] - mu) * rs * ga[j] + ba[j]);
        lnb[ks] = __builtin_bit_cast(bf16x8, pk);
    }

    // main loop: 4 quarters of 128 f each; no barriers anywhere
    f32x4 Q[8] = {};
    for (int q = 0; q < 4; ++q) {
        int fbase = q * 128;
        char* myq = lds0 + (q & 1) * 4096;
        f32x4 p[8] = {};
        #pragma unroll
        for (int ks = 0; ks < 4; ++ks) {
            #pragma unroll
            for (int tf = 0; tf < 8; ++tf) {
                bf16x8 aw = *(const bf16x8*)(W1T + (size_t)(fbase + tf * 16 + lr) * 128 + ks * 32 + lg * 8);
                p[tf] = __builtin_amdgcn_mfma_f32_16x16x32_bf16(aw, lnb[ks], p[tf], 0, 0, 0);
            }
        }
        // bias + relu + pack -> wave-private LDS (inter^T[node lr][f_local])
        #pragma unroll
        for (int tf = 0; tf < 8; ++tf) {
            float4 b1v = *(const float4*)&b1[fbase + tf * 16 + lg * 4];
            float bb[4] = {b1v.x, b1v.y, b1v.z, b1v.w};
            ushort4 pk;
            float v0 = p[tf][0] + bb[0]; pk.x = f2b(v0 > 0.f ? v0 : 0.f);
            float v1 = p[tf][1] + bb[1]; pk.y = f2b(v1 > 0.f ? v1 : 0.f);
            float v2 = p[tf][2] + bb[2]; pk.z = f2b(v2 > 0.f ? v2 : 0.f);
            float v3 = p[tf][3] + bb[3]; pk.w = f2b(v3 > 0.f ? v3 : 0.f);
            *(ushort4*)(myq + ((lr * 256 + tf * 32 + lg * 8) ^ SWZ(lr))) = pk;
        }
        // GEMM2 partial over this quarter's 128 f
        #pragma unroll
        for (int ks2 = 0; ks2 < 4; ++ks2) {
            bf16x8 bfr = *(const bf16x8*)(myq + ((lr * 256 + ks2 * 64 + lg * 16) ^ SWZ(lr)));
            #pragma unroll
            for (int tc = 0; tc < 8; ++tc) {
                bf16x8 aw2 = *(const bf16x8*)(W2T + (size_t)(tc * 16 + lr) * 512 + fbase + ks2 * 32 + lg * 8);
                Q[tc] = __builtin_amdgcn_mfma_f32_16x16x32_bf16(aw2, bfr, Q[tc], 0, 0, 0);
            }
        }
    }

    // epilogue: out[node][c] = Q^T + b2 + h  (float4 RMW, c-contiguous)
    if (ok) {
        #pragma unroll
        for (int tc = 0; tc < 8; ++tc) {
            int c = tc * 16 + lg * 4;
            float4 h4 = *(const float4*)(hrow + c);
            float4 b2v = *(const float4*)&b2[c];
            float4 o4;
            o4.x = Q[tc][0] + b2v.x + h4.x;
            o4.y = Q[tc][1] + b2v.y + h4.y;
            o4.z = Q[tc][2] + b2v.z + h4.z;
            o4.w = Q[tc][3] + b2v.w + h4.w;
            *(float4*)(out + (size_t)node * 128 + c) = o4;
        }
    }
}

extern "C" void kernel_launch(void* const* d_in, const int* in_sizes, int n_in,
                              void* d_out, int out_size, void* d_ws, size_t ws_size,
                              hipStream_t stream) {
    const float* x     = (const float*)d_in[0];
    const float* Wfc   = (const float*)d_in[1];
    const float* a_l   = (const float*)d_in[2];
    const float* a_r   = (const float*)d_in[3];
    const float* gamma = (const float*)d_in[4];
    const float* beta  = (const float*)d_in[5];
    const float* W1    = (const float*)d_in[6];
    const float* b1    = (const float*)d_in[7];
    const float* W2    = (const float*)d_in[8];
    const float* b2    = (const float*)d_in[9];
    const int*   es    = (const int*)d_in[10];
    const int*   ed    = (const int*)d_in[11];
    float* out = (float*)d_out;

    bf16_t* W1T = (bf16_t*)d_ws;                      // 512*128
    bf16_t* W2T = W1T + 512 * 128;                    // 128*512
    bf16_t* WpT = W2T + 128 * 512;                    // 128*128
    unsigned short* zb = (unsigned short*)(WpT + 128 * 128);  // N*128 bf16
    float* el = (float*)(zb + (size_t)N_NODES * 128); // N*8
    float* er = el + N_NODES * 8;                     // N*8
    int* counts  = (int*)(er + N_NODES * 8);          // N
    int* csr_off = counts + N_NODES;                  // N+1
    int* cursor  = csr_off + N_NODES + 1;             // N+1
    int* csr_src = cursor + N_NODES + 1;              // E
    int* bsum    = csr_src + E_EDGES;                 // SCAN_BLOCKS
    int* boff    = bsum + 128;                        // 128

    k_zero<<<dim3((N_NODES + 255) / 256), dim3(256), 0, stream>>>(counts);
    k_count<<<dim3((E_EDGES + 255) / 256), dim3(256), 0, stream>>>(ed, counts);
    k_scan1<<<dim3(SCAN_BLOCKS), dim3(512), 0, stream>>>(counts, bsum);
    k_scan2<<<dim3(1), dim3(128), 0, stream>>>(bsum, boff);
    k_scan3<<<dim3(SCAN_BLOCKS), dim3(512), 0, stream>>>(counts, boff, csr_off, cursor);
    k_fill<<<dim3((E_EDGES + 255) / 256), dim3(256), 0, stream>>>(es, ed, cursor, csr_src);
    k_prep<<<dim3(256), dim3(256), 0, stream>>>(W1, W2, Wfc, W1T, W2T, WpT);
    k_proj<<<dim3((N_NODES + 63) / 64), dim3(512), 0, stream>>>(x, WpT, a_l, a_r, zb, el, er);
    k_node<<<dim3(N_NODES / 8), dim3(256), 0, stream>>>(csr_off, csr_src, el, er, zb, x, out);
    k_ffn<<<dim3((N_NODES + 63) / 64), dim3(256), 0, stream>>>(gamma, beta, W1T, b1, W2T, b2, out);
}

// Round 12
// 202.495 us; speedup vs baseline: 1.4892x; 1.4892x over previous
//
#include <hip/hip_runtime.h>
#include <math.h>

#define N_NODES 50000
#define E_EDGES 800000
#define D_DIM   128
#define H_HEADS 8
#define DH_DIM  16
#define DFF     512

#define SCAN_BLOCKS 98  // 98*512 = 50176 >= N_NODES+1
#define FFN_GRID 256
#define NTILES 3125     // 50000 / 16 exactly

typedef __bf16 bf16_t;
typedef bf16_t bf16x8 __attribute__((ext_vector_type(8)));
typedef float f32x4 __attribute__((ext_vector_type(4)));
typedef unsigned short u16x8 __attribute__((ext_vector_type(8)));

#define SWZ(r) (((r) & 7) << 4)

__device__ __forceinline__ float lrelu(float v) { return v > 0.f ? v : 0.01f * v; }
__device__ __forceinline__ float elu(float v) { return v > 0.f ? v : __expf(v) - 1.f; }
__device__ __forceinline__ unsigned short f2b(float f) {
    unsigned u = __float_as_uint(f);
    unsigned r = (u + 0x7FFFu + ((u >> 16) & 1u)) >> 16;
    return (unsigned short)r;
}

// ---------------- zero counts ----------------
__global__ void k_zero(int* __restrict__ counts) {
    int i = blockIdx.x * 256 + threadIdx.x;
    if (i < N_NODES) counts[i] = 0;
}

// ---------------- count in-degree ----------------
__global__ void k_count(const int* __restrict__ ed, int* __restrict__ counts) {
    int e = blockIdx.x * 256 + threadIdx.x;
    if (e < E_EDGES) atomicAdd(&counts[ed[e]], 1);
}

// ---------------- hierarchical scan ----------------
__global__ __launch_bounds__(512) void k_scan1(const int* __restrict__ counts,
                                               int* __restrict__ bsum) {
    int i = blockIdx.x * 512 + threadIdx.x;
    int v = (i < N_NODES) ? counts[i] : 0;
    #pragma unroll
    for (int o = 1; o < 64; o <<= 1) v += __shfl_xor(v, o);
    __shared__ int ws[8];
    if ((threadIdx.x & 63) == 0) ws[threadIdx.x >> 6] = v;
    __syncthreads();
    if (threadIdx.x == 0) {
        int s = 0;
        #pragma unroll
        for (int k = 0; k < 8; ++k) s += ws[k];
        bsum[blockIdx.x] = s;
    }
}

__global__ __launch_bounds__(128) void k_scan2(const int* __restrict__ bsum,
                                               int* __restrict__ boff) {
    __shared__ int tmp[128];
    int t = threadIdx.x;
    int v = (t < SCAN_BLOCKS) ? bsum[t] : 0;
    tmp[t] = v;
    __syncthreads();
    for (int o = 1; o < 128; o <<= 1) {
        int u = (t >= o) ? tmp[t - o] : 0;
        __syncthreads();
        tmp[t] += u;
        __syncthreads();
    }
    boff[t] = (t == 0) ? 0 : tmp[t - 1];
}

__global__ __launch_bounds__(512) void k_scan3(const int* __restrict__ counts,
                                               const int* __restrict__ boff,
                                               int* __restrict__ csr_off,
                                               int* __restrict__ cursor) {
    int t = threadIdx.x;
    int i = blockIdx.x * 512 + t;
    int v = (i < N_NODES) ? counts[i] : 0;
    int lane = t & 63, w = t >> 6;
    int xs = v;
    #pragma unroll
    for (int o = 1; o < 64; o <<= 1) {
        int u = __shfl_up(xs, o);
        if (lane >= o) xs += u;
    }
    __shared__ int ws[8];
    __shared__ int wo[8];
    if (lane == 63) ws[w] = xs;
    __syncthreads();
    if (t == 0) {
        int s = 0;
        #pragma unroll
        for (int k = 0; k < 8; ++k) { wo[k] = s; s += ws[k]; }
    }
    __syncthreads();
    int excl = xs - v + wo[w] + boff[blockIdx.x];
    if (i < N_NODES) { csr_off[i] = excl; cursor[i] = excl; }
    if (i == N_NODES) csr_off[N_NODES] = E_EDGES;
}

// ---------------- fill CSR with src ids ----------------
__global__ void k_fill(const int* __restrict__ es, const int* __restrict__ ed,
                       int* __restrict__ cursor, int* __restrict__ csr_src) {
    int e = blockIdx.x * 256 + threadIdx.x;
    if (e < E_EDGES) {
        int pos = atomicAdd(&cursor[ed[e]], 1);
        csr_src[pos] = es[e];
    }
}

// ---------------- weight prep: transpose + bf16 ----------------
__global__ void k_prep(const float* __restrict__ W1, const float* __restrict__ W2,
                       const float* __restrict__ Wfc,
                       bf16_t* __restrict__ W1T, bf16_t* __restrict__ W2T,
                       bf16_t* __restrict__ WpT) {
    int id = blockIdx.x * 256 + threadIdx.x;
    if (id < 512 * 128) {
        int c = id >> 7, k = id & 127;
        W1T[id] = (bf16_t)W1[(size_t)k * 512 + c];
        int c2 = id >> 9, k2 = id & 511;
        W2T[id] = (bf16_t)W2[(size_t)k2 * 128 + c2];
        if (id < 128 * 128) {
            int cp = id >> 7, kp = id & 127;
            WpT[id] = (bf16_t)Wfc[(cp >> 4) * 2048 + kp * 16 + (cp & 15)];
        }
    }
}

// ---------------- z = x @ Wp via bf16 MFMA + fused el/er + zb ----------------
__global__ __launch_bounds__(512) void k_proj(const float* __restrict__ x,
                                              const bf16_t* __restrict__ WpT,
                                              const float* __restrict__ a_l,
                                              const float* __restrict__ a_r,
                                              unsigned short* __restrict__ zb,
                                              float* __restrict__ el,
                                              float* __restrict__ er) {
    __shared__ char xbA[16384];  // bf16[64][128], row stride 256B, swizzled
    int t = threadIdx.x;
    int r0 = blockIdx.x * 64;

    {
        int r = t >> 3, c0 = (t & 7) * 16;
        int gr = r0 + r;
        u16x8 pk0, pk1;
        if (gr < N_NODES) {
            #pragma unroll
            for (int q = 0; q < 2; ++q) {
                float4 a4 = *(const float4*)&x[(size_t)gr * 128 + c0 + q * 8];
                float4 b4 = *(const float4*)&x[(size_t)gr * 128 + c0 + q * 8 + 4];
                u16x8 pk;
                pk[0] = f2b(a4.x); pk[1] = f2b(a4.y); pk[2] = f2b(a4.z); pk[3] = f2b(a4.w);
                pk[4] = f2b(b4.x); pk[5] = f2b(b4.y); pk[6] = f2b(b4.z); pk[7] = f2b(b4.w);
                if (q == 0) pk0 = pk; else pk1 = pk;
            }
        } else {
            #pragma unroll
            for (int i = 0; i < 8; ++i) { pk0[i] = 0; pk1[i] = 0; }
        }
        int base = r * 256 + c0 * 2;
        *(u16x8*)(xbA + (base ^ SWZ(r))) = pk0;
        *(u16x8*)(xbA + ((base + 16) ^ SWZ(r))) = pk1;
    }
    __syncthreads();

    int wv = t >> 6, l = t & 63;
    int lr = l & 15, lg = l >> 4;

    f32x4 acc[4] = {};
    #pragma unroll
    for (int ks = 0; ks < 4; ++ks) {
        bf16x8 b = *(const bf16x8*)(WpT + (wv * 16 + lr) * 128 + ks * 32 + lg * 8);
        #pragma unroll
        for (int mi = 0; mi < 4; ++mi) {
            int row = mi * 16 + lr;
            int off = (row * 256 + ks * 64 + lg * 16) ^ SWZ(row);
            bf16x8 a = *(const bf16x8*)(xbA + off);
            acc[mi] = __builtin_amdgcn_mfma_f32_16x16x32_bf16(a, b, acc[mi], 0, 0, 0);
        }
    }

    float alv = a_l[wv * 16 + lr];
    float arv = a_r[wv * 16 + lr];
    float outL = 0.f, outR = 0.f;
    #pragma unroll
    for (int mi = 0; mi < 4; ++mi) {
        #pragma unroll
        for (int rg = 0; rg < 4; ++rg) {
            int row = mi * 16 + lg * 4 + rg;
            int grr = r0 + row;
            float v = acc[mi][rg];
            if (grr < N_NODES) zb[(size_t)grr * 128 + wv * 16 + lr] = f2b(v);
            float pl = v * alv, pr = v * arv;
            pl += __shfl_xor(pl, 1); pr += __shfl_xor(pr, 1);
            pl += __shfl_xor(pl, 2); pr += __shfl_xor(pr, 2);
            pl += __shfl_xor(pl, 4); pr += __shfl_xor(pr, 4);
            pl += __shfl_xor(pl, 8); pr += __shfl_xor(pr, 8);
            if (lr == mi * 4 + rg) { outL = pl; outR = pr; }
        }
    }
    int myrow = r0 + (lr >> 2) * 16 + lg * 4 + (lr & 3);
    if (myrow < N_NODES) {
        el[myrow * 8 + wv] = outL;
        er[myrow * 8 + wv] = outR;
    }
}

// ---------------- fused softmax + aggregate + elu + residual + LN -----------
// TWO nodes per wave; additionally computes ln = LN(h)*gamma+beta -> lnb bf16.
__global__ __launch_bounds__(256) void k_node(const int* __restrict__ csr_off,
                                              const int* __restrict__ csr_src,
                                              const float* __restrict__ el,
                                              const float* __restrict__ er,
                                              const unsigned short* __restrict__ zb,
                                              const float* __restrict__ x,
                                              const float* __restrict__ gamma,
                                              const float* __restrict__ beta,
                                              unsigned short* __restrict__ lnb,
                                              float* __restrict__ out) {
    int n = blockIdx.x * 8 + (threadIdx.x >> 5);
    int lane = threadIdx.x & 63;
    int q = lane & 31;
    int base = lane & 32;       // shuffle base of this half-wave
    int h = q >> 2, s = q & 3;
    int row = csr_off[n];
    int deg = csr_off[n + 1] - row;
    float4 xv = *(const float4*)&x[(size_t)n * 128 + q * 4];
    float erv = er[n * 8 + h];
    int nch = (deg + 3) >> 2;

    float ev[8];
    int srcv[8];
    float mx = -INFINITY;
    #pragma unroll
    for (int c = 0; c < 8; ++c) {
        int k = c * 4 + s;
        int src = 0;
        float e = -INFINITY;
        if (c * 4 < deg) {  // uniform across half-wave
            if (k < deg) {
                src = csr_src[row + k];
                e = lrelu(el[src * 8 + h] + erv);
            }
        }
        ev[c] = e;
        srcv[c] = src;
        mx = fmaxf(mx, e);
    }
    for (int c = 8; c < nch; ++c) {  // rare: deg > 32
        int k = c * 4 + s;
        if (k < deg) {
            int src = csr_src[row + k];
            mx = fmaxf(mx, lrelu(el[src * 8 + h] + erv));
        }
    }
    mx = fmaxf(mx, __shfl_xor(mx, 1));
    mx = fmaxf(mx, __shfl_xor(mx, 2));

    float ps = 0.f;
    float ac0 = 0.f, ac1 = 0.f, ac2 = 0.f, ac3 = 0.f;
    const unsigned short* zbl = zb + q * 4;
    #pragma unroll
    for (int c = 0; c < 8; ++c) {
        if (c * 4 < deg) {  // uniform across half-wave
            float p = ((c * 4 + s) < deg) ? __expf(ev[c] - mx) : 0.f;
            ps += p;
            float a[4];
            int se[4];
            #pragma unroll
            for (int tt = 0; tt < 4; ++tt) {
                a[tt] = __shfl(p, base + h * 4 + tt);
                se[tt] = __shfl(srcv[c], base + tt);
            }
            uint2 u[4];
            #pragma unroll
            for (int tt = 0; tt < 4; ++tt)
                u[tt] = *(const uint2*)(zbl + (size_t)se[tt] * 128);
            #pragma unroll
            for (int tt = 0; tt < 4; ++tt) {
                ac0 += a[tt] * __uint_as_float(u[tt].x << 16);
                ac1 += a[tt] * __uint_as_float(u[tt].x & 0xFFFF0000u);
                ac2 += a[tt] * __uint_as_float(u[tt].y << 16);
                ac3 += a[tt] * __uint_as_float(u[tt].y & 0xFFFF0000u);
            }
        }
    }
    for (int c = 8; c < nch; ++c) {  // rare: deg > 32
        int k = c * 4 + s;
        int src = 0;
        float e = -INFINITY;
        if (k < deg) {
            src = csr_src[row + k];
            e = lrelu(el[src * 8 + h] + erv);
        }
        float p = (k < deg) ? __expf(e - mx) : 0.f;
        ps += p;
        float a[4];
        int se[4];
        #pragma unroll
        for (int tt = 0; tt < 4; ++tt) {
            a[tt] = __shfl(p, base + h * 4 + tt);
            se[tt] = __shfl(src, base + tt);
        }
        uint2 u[4];
        #pragma unroll
        for (int tt = 0; tt < 4; ++tt)
            u[tt] = *(const uint2*)(zbl + (size_t)se[tt] * 128);
        #pragma unroll
        for (int tt = 0; tt < 4; ++tt) {
            ac0 += a[tt] * __uint_as_float(u[tt].x << 16);
            ac1 += a[tt] * __uint_as_float(u[tt].x & 0xFFFF0000u);
            ac2 += a[tt] * __uint_as_float(u[tt].y << 16);
            ac3 += a[tt] * __uint_as_float(u[tt].y & 0xFFFF0000u);
        }
    }
    ps += __shfl_xor(ps, 1);
    ps += __shfl_xor(ps, 2);
    float inv = 1.f / fmaxf(ps, 1e-9f);
    float4 hv;
    hv.x = xv.x + elu(ac0 * inv);
    hv.y = xv.y + elu(ac1 * inv);
    hv.z = xv.z + elu(ac2 * inv);
    hv.w = xv.w + elu(ac3 * inv);
    *(float4*)&out[(size_t)n * 128 + q * 4] = hv;

    // LayerNorm over the 128 dims held by this half-wave (32 lanes x 4)
    float rsm = hv.x + hv.y + hv.z + hv.w;
    float rsq = hv.x * hv.x + hv.y * hv.y + hv.z * hv.z + hv.w * hv.w;
    #pragma unroll
    for (int o = 1; o <= 16; o <<= 1) {
        rsm += __shfl_xor(rsm, o);
        rsq += __shfl_xor(rsq, o);
    }
    float mu = rsm * (1.f / 128.f);
    float rs = rsqrtf(rsq * (1.f / 128.f) - mu * mu + 1e-5f);
    float4 g4 = *(const float4*)&gamma[q * 4];
    float4 be4 = *(const float4*)&beta[q * 4];
    ushort4 pk;
    pk.x = f2b((hv.x - mu) * rs * g4.x + be4.x);
    pk.y = f2b((hv.y - mu) * rs * g4.y + be4.y);
    pk.z = f2b((hv.z - mu) * rs * g4.z + be4.z);
    pk.w = f2b((hv.w - mu) * rs * g4.w + be4.w);
    *(ushort4*)&lnb[(size_t)n * 128 + q * 4] = pk;
}

// ---------------- FFN: weight-stationary persistent kernel -----------------
// 256 blocks x 256 threads, 1 wave/SIMD (512-VGPR budget). Each wave persists
// its W1/W2 A-fragments in registers (256 VGPR); grid-strides over 16-node
// tiles. GEMM1 swapped (inter^T = W1T.ln^T), inter^T through 16KB swizzled
// LDS, GEMM2 swapped (out^T = W2T.inter^T). ln B-frags prefetched 1 tile
// ahead; h prefetched at tile top. 2 barriers/tile (4 waves).
__global__ __launch_bounds__(256, 1) void k_ffn(const bf16_t* __restrict__ W1T,
                                                const float* __restrict__ b1,
                                                const bf16_t* __restrict__ W2T,
                                                const float* __restrict__ b2,
                                                const unsigned short* __restrict__ lnb,
                                                float* __restrict__ out) {
    __shared__ char inA[16384];  // bf16[16 nodes][512 f], row 1024B, swz by node
    int t = threadIdx.x;
    int w = t >> 6, l = t & 63;
    int lr = l & 15, lg = l >> 4;

    // persistent W1 fragments: A[row = w*128 + tf*16 + lr][k = ks*32 + lg*8]
    bf16x8 w1f[4][8];
    #pragma unroll
    for (int ks = 0; ks < 4; ++ks)
        #pragma unroll
        for (int tf = 0; tf < 8; ++tf)
            w1f[ks][tf] = *(const bf16x8*)(W1T + (size_t)(w * 128 + tf * 16 + lr) * 128 + ks * 32 + lg * 8);
    // persistent W2 fragments: A[row = w*32 + tc*16 + lr][k(f) = ks2*32 + lg*8]
    bf16x8 w2f[16][2];
    #pragma unroll
    for (int ks2 = 0; ks2 < 16; ++ks2)
        #pragma unroll
        for (int tc = 0; tc < 2; ++tc)
            w2f[ks2][tc] = *(const bf16x8*)(W2T + (size_t)(w * 32 + tc * 16 + lr) * 512 + ks2 * 32 + lg * 8);
    // persistent bias fragments
    float4 b1v[8];
    #pragma unroll
    for (int tf = 0; tf < 8; ++tf)
        b1v[tf] = *(const float4*)&b1[w * 128 + tf * 16 + lg * 4];
    float4 b2v[2];
    #pragma unroll
    for (int tc = 0; tc < 2; ++tc)
        b2v[tc] = *(const float4*)&b2[w * 32 + tc * 16 + lg * 4];

    int tile = blockIdx.x;
    bf16x8 cur[4];
    #pragma unroll
    for (int ks = 0; ks < 4; ++ks)
        cur[ks] = *(const bf16x8*)(lnb + (size_t)(tile * 16 + lr) * 128 + ks * 32 + lg * 8);

    while (tile < NTILES) {
        // prefetch h rows for epilogue (this tile, this lane's c-slice)
        float4 h4[2];
        #pragma unroll
        for (int tc = 0; tc < 2; ++tc)
            h4[tc] = *(const float4*)(out + (size_t)(tile * 16 + lr) * 128 + w * 32 + tc * 16 + lg * 4);

        // GEMM1: inter^T(f, node) for f in wave's 128-slice
        f32x4 p[8] = {};
        #pragma unroll
        for (int ks = 0; ks < 4; ++ks)
            #pragma unroll
            for (int tf = 0; tf < 8; ++tf)
                p[tf] = __builtin_amdgcn_mfma_f32_16x16x32_bf16(w1f[ks][tf], cur[ks], p[tf], 0, 0, 0);

        // prefetch next tile's ln fragments
        int tn = tile + FFN_GRID;
        if (tn < NTILES) {
            #pragma unroll
            for (int ks = 0; ks < 4; ++ks)
                cur[ks] = *(const bf16x8*)(lnb + (size_t)(tn * 16 + lr) * 128 + ks * 32 + lg * 8);
        }

        // bias + relu -> inA (ushort4 along f, swizzled by node row)
        #pragma unroll
        for (int tf = 0; tf < 8; ++tf) {
            float4 bb = b1v[tf];
            ushort4 pk;
            float v0 = p[tf][0] + bb.x; pk.x = f2b(v0 > 0.f ? v0 : 0.f);
            float v1 = p[tf][1] + bb.y; pk.y = f2b(v1 > 0.f ? v1 : 0.f);
            float v2 = p[tf][2] + bb.z; pk.z = f2b(v2 > 0.f ? v2 : 0.f);
            float v3 = p[tf][3] + bb.w; pk.w = f2b(v3 > 0.f ? v3 : 0.f);
            *(ushort4*)(inA + ((lr * 1024 + w * 256 + tf * 32 + lg * 8) ^ SWZ(lr))) = pk;
        }
        __syncthreads();

        // GEMM2: out^T(c, node) partial over all 512 f; wave's 32-c slice
        f32x4 Q[2] = {};
        #pragma unroll
        for (int ks2 = 0; ks2 < 16; ++ks2) {
            bf16x8 bfr = *(const bf16x8*)(inA + ((lr * 1024 + ks2 * 64 + lg * 16) ^ SWZ(lr)));
            #pragma unroll
            for (int tc = 0; tc < 2; ++tc)
                Q[tc] = __builtin_amdgcn_mfma_f32_16x16x32_bf16(w2f[ks2][tc], bfr, Q[tc], 0, 0, 0);
        }

        // epilogue: out[node][c] = Q + b2 + h
        #pragma unroll
        for (int tc = 0; tc < 2; ++tc) {
            float4 o4;
            o4.x = Q[tc][0] + b2v[tc].x + h4[tc].x;
            o4.y = Q[tc][1] + b2v[tc].y + h4[tc].y;
            o4.z = Q[tc][2] + b2v[tc].z + h4[tc].z;
            o4.w = Q[tc][3] + b2v[tc].w + h4[tc].w;
            *(float4*)(out + (size_t)(tile * 16 + lr) * 128 + w * 32 + tc * 16 + lg * 4) = o4;
        }
        __syncthreads();
        tile = tn;
    }
}

extern "C" void kernel_launch(void* const* d_in, const int* in_sizes, int n_in,
                              void* d_out, int out_size, void* d_ws, size_t ws_size,
                              hipStream_t stream) {
    const float* x     = (const float*)d_in[0];
    const float* Wfc   = (const float*)d_in[1];
    const float* a_l   = (const float*)d_in[2];
    const float* a_r   = (const float*)d_in[3];
    const float* gamma = (const float*)d_in[4];
    const float* beta  = (const float*)d_in[5];
    const float* W1    = (const float*)d_in[6];
    const float* b1    = (const float*)d_in[7];
    const float* W2    = (const float*)d_in[8];
    const float* b2    = (const float*)d_in[9];
    const int*   es    = (const int*)d_in[10];
    const int*   ed    = (const int*)d_in[11];
    float* out = (float*)d_out;

    bf16_t* W1T = (bf16_t*)d_ws;                      // 512*128
    bf16_t* W2T = W1T + 512 * 128;                    // 128*512
    bf16_t* WpT = W2T + 128 * 512;                    // 128*128
    unsigned short* zb = (unsigned short*)(WpT + 128 * 128);  // N*128 bf16
    float* el = (float*)(zb + (size_t)N_NODES * 128); // N*8
    float* er = el + N_NODES * 8;                     // N*8
    int* counts  = (int*)(er + N_NODES * 8);          // N
    int* csr_off = counts + N_NODES;                  // N+1
    int* cursor  = csr_off + N_NODES + 1;             // N+1
    int* csr_src = cursor + N_NODES + 1;              // E
    int* bsum    = csr_src + E_EDGES;                 // SCAN_BLOCKS
    int* boff    = bsum + 128;                        // 128
    unsigned short* lnbuf = (unsigned short*)(boff + 128);  // N*128 bf16

    k_zero<<<dim3((N_NODES + 255) / 256), dim3(256), 0, stream>>>(counts);
    k_count<<<dim3((E_EDGES + 255) / 256), dim3(256), 0, stream>>>(ed, counts);
    k_scan1<<<dim3(SCAN_BLOCKS), dim3(512), 0, stream>>>(counts, bsum);
    k_scan2<<<dim3(1), dim3(128), 0, stream>>>(bsum, boff);
    k_scan3<<<dim3(SCAN_BLOCKS), dim3(512), 0, stream>>>(counts, boff, csr_off, cursor);
    k_fill<<<dim3((E_EDGES + 255) / 256), dim3(256), 0, stream>>>(es, ed, cursor, csr_src);
    k_prep<<<dim3(256), dim3(256), 0, stream>>>(W1, W2, Wfc, W1T, W2T, WpT);
    k_proj<<<dim3((N_NODES + 63) / 64), dim3(512), 0, stream>>>(x, WpT, a_l, a_r, zb, el, er);
    k_node<<<dim3(N_NODES / 8), dim3(256), 0, stream>>>(csr_off, csr_src, el, er, zb, x,
                                                        gamma, beta, lnbuf, out);
    k_ffn<<<dim3(FFN_GRID), dim3(256), 0, stream>>>(W1T, b1, W2T, b2, lnbuf, out);
}

// Round 13
// 154.202 us; speedup vs baseline: 1.9556x; 1.3132x over previous
//
#include <hip/hip_runtime.h>
#include <math.h>

#define N_NODES 50000
#define E_EDGES 800000
#define D_DIM   128
#define H_HEADS 8
#define DH_DIM  16
#define DFF     512

#define SCAN_BLOCKS 98  // 98*512 = 50176 >= N_NODES+1
#define FFN_GRID 256
#define NTILES 3125     // 50000 / 16 exactly
#define PROJ_BLOCKS 782 // ceil(50000/64)
#define FILL_BLOCKS 782 // ceil(800000/1024)

typedef __bf16 bf16_t;
typedef bf16_t bf16x8 __attribute__((ext_vector_type(8)));
typedef float f32x4 __attribute__((ext_vector_type(4)));
typedef unsigned short u16x8 __attribute__((ext_vector_type(8)));

#define SWZ(r) (((r) & 7) << 4)

__device__ __forceinline__ float lrelu(float v) { return v > 0.f ? v : 0.01f * v; }
__device__ __forceinline__ float elu(float v) { return v > 0.f ? v : __expf(v) - 1.f; }
__device__ __forceinline__ unsigned short f2b(float f) {
    unsigned u = __float_as_uint(f);
    unsigned r = (u + 0x7FFFu + ((u >> 16) & 1u)) >> 16;
    return (unsigned short)r;
}

// ---------------- zero counts ----------------
__global__ void k_zero(int* __restrict__ counts) {
    int i = blockIdx.x * 256 + threadIdx.x;
    if (i < N_NODES) counts[i] = 0;
}

// ---------------- count in-degree + capture rank ----------------
__global__ void k_count(const int* __restrict__ ed, int* __restrict__ counts,
                        int* __restrict__ rank) {
    int e = blockIdx.x * 256 + threadIdx.x;
    if (e < E_EDGES) rank[e] = atomicAdd(&counts[ed[e]], 1);
}

// ---------------- hierarchical scan ----------------
__global__ __launch_bounds__(512) void k_scan1(const int* __restrict__ counts,
                                               int* __restrict__ bsum) {
    int i = blockIdx.x * 512 + threadIdx.x;
    int v = (i < N_NODES) ? counts[i] : 0;
    #pragma unroll
    for (int o = 1; o < 64; o <<= 1) v += __shfl_xor(v, o);
    __shared__ int ws[8];
    if ((threadIdx.x & 63) == 0) ws[threadIdx.x >> 6] = v;
    __syncthreads();
    if (threadIdx.x == 0) {
        int s = 0;
        #pragma unroll
        for (int k = 0; k < 8; ++k) s += ws[k];
        bsum[blockIdx.x] = s;
    }
}

__global__ __launch_bounds__(128) void k_scan2(const int* __restrict__ bsum,
                                               int* __restrict__ boff) {
    __shared__ int tmp[128];
    int t = threadIdx.x;
    int v = (t < SCAN_BLOCKS) ? bsum[t] : 0;
    tmp[t] = v;
    __syncthreads();
    for (int o = 1; o < 128; o <<= 1) {
        int u = (t >= o) ? tmp[t - o] : 0;
        __syncthreads();
        tmp[t] += u;
        __syncthreads();
    }
    boff[t] = (t == 0) ? 0 : tmp[t - 1];
}

__global__ __launch_bounds__(512) void k_scan3(const int* __restrict__ counts,
                                               const int* __restrict__ boff,
                                               int* __restrict__ csr_off) {
    int t = threadIdx.x;
    int i = blockIdx.x * 512 + t;
    int v = (i < N_NODES) ? counts[i] : 0;
    int lane = t & 63, w = t >> 6;
    int xs = v;
    #pragma unroll
    for (int o = 1; o < 64; o <<= 1) {
        int u = __shfl_up(xs, o);
        if (lane >= o) xs += u;
    }
    __shared__ int ws[8];
    __shared__ int wo[8];
    if (lane == 63) ws[w] = xs;
    __syncthreads();
    if (t == 0) {
        int s = 0;
        #pragma unroll
        for (int k = 0; k < 8; ++k) { wo[k] = s; s += ws[k]; }
    }
    __syncthreads();
    int excl = xs - v + wo[w] + boff[blockIdx.x];
    if (i < N_NODES) csr_off[i] = excl;
    if (i == N_NODES) csr_off[N_NODES] = E_EDGES;
}

// ---------------- weight prep: transpose + bf16 ----------------
__global__ void k_prep(const float* __restrict__ W1, const float* __restrict__ W2,
                       const float* __restrict__ Wfc,
                       bf16_t* __restrict__ W1T, bf16_t* __restrict__ W2T,
                       bf16_t* __restrict__ WpT) {
    int id = blockIdx.x * 256 + threadIdx.x;
    if (id < 512 * 128) {
        int c = id >> 7, k = id & 127;
        W1T[id] = (bf16_t)W1[(size_t)k * 512 + c];
        int c2 = id >> 9, k2 = id & 511;
        W2T[id] = (bf16_t)W2[(size_t)k2 * 128 + c2];
        if (id < 128 * 128) {
            int cp = id >> 7, kp = id & 127;
            WpT[id] = (bf16_t)Wfc[(cp >> 4) * 2048 + kp * 16 + (cp & 15)];
        }
    }
}

// ---------------- FUSED: proj (MFMA) blocks || CSR-fill (scatter) blocks ----
// Independent dependency chains overlap: proj is MFMA/LDS-bound, fill is
// scatter/BW-bound. Fill is atomic-free (rank captured in k_count).
__global__ __launch_bounds__(512) void k_fillproj(const float* __restrict__ x,
                                                  const bf16_t* __restrict__ WpT,
                                                  const float* __restrict__ a_l,
                                                  const float* __restrict__ a_r,
                                                  unsigned short* __restrict__ zb,
                                                  float* __restrict__ el,
                                                  float* __restrict__ er,
                                                  const int* __restrict__ es,
                                                  const int* __restrict__ ed,
                                                  const int* __restrict__ rank,
                                                  const int* __restrict__ csr_off,
                                                  int* __restrict__ csr_src) {
    __shared__ char xbA[16384];  // bf16[64][128], row stride 256B, swizzled
    int t = threadIdx.x;

    if (blockIdx.x >= PROJ_BLOCKS) {
        // ---- fill branch: 1024 edges/block, no atomics ----
        int e0 = (blockIdx.x - PROJ_BLOCKS) * 1024 + t;
        #pragma unroll
        for (int k = 0; k < 2; ++k) {
            int e = e0 + k * 512;
            if (e < E_EDGES) {
                int d = ed[e];
                csr_src[csr_off[d] + rank[e]] = es[e];
            }
        }
        return;
    }

    // ---- proj branch ----
    int r0 = blockIdx.x * 64;
    {
        int r = t >> 3, c0 = (t & 7) * 16;
        int gr = r0 + r;
        u16x8 pk0, pk1;
        if (gr < N_NODES) {
            #pragma unroll
            for (int q = 0; q < 2; ++q) {
                float4 a4 = *(const float4*)&x[(size_t)gr * 128 + c0 + q * 8];
                float4 b4 = *(const float4*)&x[(size_t)gr * 128 + c0 + q * 8 + 4];
                u16x8 pk;
                pk[0] = f2b(a4.x); pk[1] = f2b(a4.y); pk[2] = f2b(a4.z); pk[3] = f2b(a4.w);
                pk[4] = f2b(b4.x); pk[5] = f2b(b4.y); pk[6] = f2b(b4.z); pk[7] = f2b(b4.w);
                if (q == 0) pk0 = pk; else pk1 = pk;
            }
        } else {
            #pragma unroll
            for (int i = 0; i < 8; ++i) { pk0[i] = 0; pk1[i] = 0; }
        }
        int base = r * 256 + c0 * 2;
        *(u16x8*)(xbA + (base ^ SWZ(r))) = pk0;
        *(u16x8*)(xbA + ((base + 16) ^ SWZ(r))) = pk1;
    }
    __syncthreads();

    int wv = t >> 6, l = t & 63;
    int lr = l & 15, lg = l >> 4;

    f32x4 acc[4] = {};
    #pragma unroll
    for (int ks = 0; ks < 4; ++ks) {
        bf16x8 b = *(const bf16x8*)(WpT + (wv * 16 + lr) * 128 + ks * 32 + lg * 8);
        #pragma unroll
        for (int mi = 0; mi < 4; ++mi) {
            int row = mi * 16 + lr;
            int off = (row * 256 + ks * 64 + lg * 16) ^ SWZ(row);
            bf16x8 a = *(const bf16x8*)(xbA + off);
            acc[mi] = __builtin_amdgcn_mfma_f32_16x16x32_bf16(a, b, acc[mi], 0, 0, 0);
        }
    }

    float alv = a_l[wv * 16 + lr];
    float arv = a_r[wv * 16 + lr];
    float outL = 0.f, outR = 0.f;
    #pragma unroll
    for (int mi = 0; mi < 4; ++mi) {
        #pragma unroll
        for (int rg = 0; rg < 4; ++rg) {
            int row = mi * 16 + lg * 4 + rg;
            int grr = r0 + row;
            float v = acc[mi][rg];
            if (grr < N_NODES) zb[(size_t)grr * 128 + wv * 16 + lr] = f2b(v);
            float pl = v * alv, pr = v * arv;
            pl += __shfl_xor(pl, 1); pr += __shfl_xor(pr, 1);
            pl += __shfl_xor(pl, 2); pr += __shfl_xor(pr, 2);
            pl += __shfl_xor(pl, 4); pr += __shfl_xor(pr, 4);
            pl += __shfl_xor(pl, 8); pr += __shfl_xor(pr, 8);
            if (lr == mi * 4 + rg) { outL = pl; outR = pr; }
        }
    }
    int myrow = r0 + (lr >> 2) * 16 + lg * 4 + (lr & 3);
    if (myrow < N_NODES) {
        el[myrow * 8 + wv] = outL;
        er[myrow * 8 + wv] = outR;
    }
}

// ---------------- fused softmax + aggregate + elu + residual + LN -----------
__global__ __launch_bounds__(256) void k_node(const int* __restrict__ csr_off,
                                              const int* __restrict__ csr_src,
                                              const float* __restrict__ el,
                                              const float* __restrict__ er,
                                              const unsigned short* __restrict__ zb,
                                              const float* __restrict__ x,
                                              const float* __restrict__ gamma,
                                              const float* __restrict__ beta,
                                              unsigned short* __restrict__ lnb,
                                              float* __restrict__ out) {
    int n = blockIdx.x * 8 + (threadIdx.x >> 5);
    int lane = threadIdx.x & 63;
    int q = lane & 31;
    int base = lane & 32;       // shuffle base of this half-wave
    int h = q >> 2, s = q & 3;
    int row = csr_off[n];
    int deg = csr_off[n + 1] - row;
    float4 xv = *(const float4*)&x[(size_t)n * 128 + q * 4];
    float erv = er[n * 8 + h];
    int nch = (deg + 3) >> 2;

    float ev[8];
    int srcv[8];
    float mx = -INFINITY;
    #pragma unroll
    for (int c = 0; c < 8; ++c) {
        int k = c * 4 + s;
        int src = 0;
        float e = -INFINITY;
        if (c * 4 < deg) {  // uniform across half-wave
            if (k < deg) {
                src = csr_src[row + k];
                e = lrelu(el[src * 8 + h] + erv);
            }
        }
        ev[c] = e;
        srcv[c] = src;
        mx = fmaxf(mx, e);
    }
    for (int c = 8; c < nch; ++c) {  // rare: deg > 32
        int k = c * 4 + s;
        if (k < deg) {
            int src = csr_src[row + k];
            mx = fmaxf(mx, lrelu(el[src * 8 + h] + erv));
        }
    }
    mx = fmaxf(mx, __shfl_xor(mx, 1));
    mx = fmaxf(mx, __shfl_xor(mx, 2));

    float ps = 0.f;
    float ac0 = 0.f, ac1 = 0.f, ac2 = 0.f, ac3 = 0.f;
    const unsigned short* zbl = zb + q * 4;
    #pragma unroll
    for (int c = 0; c < 8; ++c) {
        if (c * 4 < deg) {  // uniform across half-wave
            float p = ((c * 4 + s) < deg) ? __expf(ev[c] - mx) : 0.f;
            ps += p;
            float a[4];
            int se[4];
            #pragma unroll
            for (int tt = 0; tt < 4; ++tt) {
                a[tt] = __shfl(p, base + h * 4 + tt);
                se[tt] = __shfl(srcv[c], base + tt);
            }
            uint2 u[4];
            #pragma unroll
            for (int tt = 0; tt < 4; ++tt)
                u[tt] = *(const uint2*)(zbl + (size_t)se[tt] * 128);
            #pragma unroll
            for (int tt = 0; tt < 4; ++tt) {
                ac0 += a[tt] * __uint_as_float(u[tt].x << 16);
                ac1 += a[tt] * __uint_as_float(u[tt].x & 0xFFFF0000u);
                ac2 += a[tt] * __uint_as_float(u[tt].y << 16);
                ac3 += a[tt] * __uint_as_float(u[tt].y & 0xFFFF0000u);
            }
        }
    }
    for (int c = 8; c < nch; ++c) {  // rare: deg > 32
        int k = c * 4 + s;
        int src = 0;
        float e = -INFINITY;
        if (k < deg) {
            src = csr_src[row + k];
            e = lrelu(el[src * 8 + h] + erv);
        }
        float p = (k < deg) ? __expf(e - mx) : 0.f;
        ps += p;
        float a[4];
        int se[4];
        #pragma unroll
        for (int tt = 0; tt < 4; ++tt) {
            a[tt] = __shfl(p, base + h * 4 + tt);
            se[tt] = __shfl(src, base + tt);
        }
        uint2 u[4];
        #pragma unroll
        for (int tt = 0; tt < 4; ++tt)
            u[tt] = *(const uint2*)(zbl + (size_t)se[tt] * 128);
        #pragma unroll
        for (int tt = 0; tt < 4; ++tt) {
            ac0 += a[tt] * __uint_as_float(u[tt].x << 16);
            ac1 += a[tt] * __uint_as_float(u[tt].x & 0xFFFF0000u);
            ac2 += a[tt] * __uint_as_float(u[tt].y << 16);
            ac3 += a[tt] * __uint_as_float(u[tt].y & 0xFFFF0000u);
        }
    }
    ps += __shfl_xor(ps, 1);
    ps += __shfl_xor(ps, 2);
    float inv = 1.f / fmaxf(ps, 1e-9f);
    float4 hv;
    hv.x = xv.x + elu(ac0 * inv);
    hv.y = xv.y + elu(ac1 * inv);
    hv.z = xv.z + elu(ac2 * inv);
    hv.w = xv.w + elu(ac3 * inv);
    *(float4*)&out[(size_t)n * 128 + q * 4] = hv;

    // LayerNorm over the 128 dims held by this half-wave (32 lanes x 4)
    float rsm = hv.x + hv.y + hv.z + hv.w;
    float rsq = hv.x * hv.x + hv.y * hv.y + hv.z * hv.z + hv.w * hv.w;
    #pragma unroll
    for (int o = 1; o <= 16; o <<= 1) {
        rsm += __shfl_xor(rsm, o);
        rsq += __shfl_xor(rsq, o);
    }
    float mu = rsm * (1.f / 128.f);
    float rs = rsqrtf(rsq * (1.f / 128.f) - mu * mu + 1e-5f);
    float4 g4 = *(const float4*)&gamma[q * 4];
    float4 be4 = *(const float4*)&beta[q * 4];
    ushort4 pk;
    pk.x = f2b((hv.x - mu) * rs * g4.x + be4.x);
    pk.y = f2b((hv.y - mu) * rs * g4.y + be4.y);
    pk.z = f2b((hv.z - mu) * rs * g4.z + be4.z);
    pk.w = f2b((hv.w - mu) * rs * g4.w + be4.w);
    *(ushort4*)&lnb[(size_t)n * 128 + q * 4] = pk;
}

// ---------------- FFN: weight-stationary persistent kernel -----------------
__global__ __launch_bounds__(256, 1) void k_ffn(const bf16_t* __restrict__ W1T,
                                                const float* __restrict__ b1,
                                                const bf16_t* __restrict__ W2T,
                                                const float* __restrict__ b2,
                                                const unsigned short* __restrict__ lnb,
                                                float* __restrict__ out) {
    __shared__ char inA[16384];  // bf16[16 nodes][512 f], row 1024B, swz by node
    int t = threadIdx.x;
    int w = t >> 6, l = t & 63;
    int lr = l & 15, lg = l >> 4;

    bf16x8 w1f[4][8];
    #pragma unroll
    for (int ks = 0; ks < 4; ++ks)
        #pragma unroll
        for (int tf = 0; tf < 8; ++tf)
            w1f[ks][tf] = *(const bf16x8*)(W1T + (size_t)(w * 128 + tf * 16 + lr) * 128 + ks * 32 + lg * 8);
    bf16x8 w2f[16][2];
    #pragma unroll
    for (int ks2 = 0; ks2 < 16; ++ks2)
        #pragma unroll
        for (int tc = 0; tc < 2; ++tc)
            w2f[ks2][tc] = *(const bf16x8*)(W2T + (size_t)(w * 32 + tc * 16 + lr) * 512 + ks2 * 32 + lg * 8);
    float4 b1v[8];
    #pragma unroll
    for (int tf = 0; tf < 8; ++tf)
        b1v[tf] = *(const float4*)&b1[w * 128 + tf * 16 + lg * 4];
    float4 b2v[2];
    #pragma unroll
    for (int tc = 0; tc < 2; ++tc)
        b2v[tc] = *(const float4*)&b2[w * 32 + tc * 16 + lg * 4];

    int tile = blockIdx.x;
    bf16x8 cur[4];
    #pragma unroll
    for (int ks = 0; ks < 4; ++ks)
        cur[ks] = *(const bf16x8*)(lnb + (size_t)(tile * 16 + lr) * 128 + ks * 32 + lg * 8);

    while (tile < NTILES) {
        float4 h4[2];
        #pragma unroll
        for (int tc = 0; tc < 2; ++tc)
            h4[tc] = *(const float4*)(out + (size_t)(tile * 16 + lr) * 128 + w * 32 + tc * 16 + lg * 4);

        f32x4 p[8] = {};
        #pragma unroll
        for (int ks = 0; ks < 4; ++ks)
            #pragma unroll
            for (int tf = 0; tf < 8; ++tf)
                p[tf] = __builtin_amdgcn_mfma_f32_16x16x32_bf16(w1f[ks][tf], cur[ks], p[tf], 0, 0, 0);

        int tn = tile + FFN_GRID;
        if (tn < NTILES) {
            #pragma unroll
            for (int ks = 0; ks < 4; ++ks)
                cur[ks] = *(const bf16x8*)(lnb + (size_t)(tn * 16 + lr) * 128 + ks * 32 + lg * 8);
        }

        #pragma unroll
        for (int tf = 0; tf < 8; ++tf) {
            float4 bb = b1v[tf];
            ushort4 pk;
            float v0 = p[tf][0] + bb.x; pk.x = f2b(v0 > 0.f ? v0 : 0.f);
            float v1 = p[tf][1] + bb.y; pk.y = f2b(v1 > 0.f ? v1 : 0.f);
            float v2 = p[tf][2] + bb.z; pk.z = f2b(v2 > 0.f ? v2 : 0.f);
            float v3 = p[tf][3] + bb.w; pk.w = f2b(v3 > 0.f ? v3 : 0.f);
            *(ushort4*)(inA + ((lr * 1024 + w * 256 + tf * 32 + lg * 8) ^ SWZ(lr))) = pk;
        }
        __syncthreads();

        f32x4 Q[2] = {};
        #pragma unroll
        for (int ks2 = 0; ks2 < 16; ++ks2) {
            bf16x8 bfr = *(const bf16x8*)(inA + ((lr * 1024 + ks2 * 64 + lg * 16) ^ SWZ(lr)));
            #pragma unroll
            for (int tc = 0; tc < 2; ++tc)
                Q[tc] = __builtin_amdgcn_mfma_f32_16x16x32_bf16(w2f[ks2][tc], bfr, Q[tc], 0, 0, 0);
        }

        #pragma unroll
        for (int tc = 0; tc < 2; ++tc) {
            float4 o4;
            o4.x = Q[tc][0] + b2v[tc].x + h4[tc].x;
            o4.y = Q[tc][1] + b2v[tc].y + h4[tc].y;
            o4.z = Q[tc][2] + b2v[tc].z + h4[tc].z;
            o4.w = Q[tc][3] + b2v[tc].w + h4[tc].w;
            *(float4*)(out + (size_t)(tile * 16 + lr) * 128 + w * 32 + tc * 16 + lg * 4) = o4;
        }
        __syncthreads();
        tile = tn;
    }
}

extern "C" void kernel_launch(void* const* d_in, const int* in_sizes, int n_in,
                              void* d_out, int out_size, void* d_ws, size_t ws_size,
                              hipStream_t stream) {
    const float* x     = (const float*)d_in[0];
    const float* Wfc   = (const float*)d_in[1];
    const float* a_l   = (const float*)d_in[2];
    const float* a_r   = (const float*)d_in[3];
    const float* gamma = (const float*)d_in[4];
    const float* beta  = (const float*)d_in[5];
    const float* W1    = (const float*)d_in[6];
    const float* b1    = (const float*)d_in[7];
    const float* W2    = (const float*)d_in[8];
    const float* b2    = (const float*)d_in[9];
    const int*   es    = (const int*)d_in[10];
    const int*   ed    = (const int*)d_in[11];
    float* out = (float*)d_out;

    bf16_t* W1T = (bf16_t*)d_ws;                      // 512*128
    bf16_t* W2T = W1T + 512 * 128;                    // 128*512
    bf16_t* WpT = W2T + 128 * 512;                    // 128*128
    unsigned short* zb = (unsigned short*)(WpT + 128 * 128);  // N*128 bf16
    float* el = (float*)(zb + (size_t)N_NODES * 128); // N*8
    float* er = el + N_NODES * 8;                     // N*8
    int* counts  = (int*)(er + N_NODES * 8);          // N
    int* csr_off = counts + N_NODES;                  // N+1
    int* csr_src = csr_off + N_NODES + 1;             // E
    int* rank    = csr_src + E_EDGES;                 // E
    int* bsum    = rank + E_EDGES;                    // 128
    int* boff    = bsum + 128;                        // 128
    unsigned short* lnbuf = (unsigned short*)(boff + 128);  // N*128 bf16

    k_prep<<<dim3(256), dim3(256), 0, stream>>>(W1, W2, Wfc, W1T, W2T, WpT);
    k_zero<<<dim3((N_NODES + 255) / 256), dim3(256), 0, stream>>>(counts);
    k_count<<<dim3((E_EDGES + 255) / 256), dim3(256), 0, stream>>>(ed, counts, rank);
    k_scan1<<<dim3(SCAN_BLOCKS), dim3(512), 0, stream>>>(counts, bsum);
    k_scan2<<<dim3(1), dim3(128), 0, stream>>>(bsum, boff);
    k_scan3<<<dim3(SCAN_BLOCKS), dim3(512), 0, stream>>>(counts, boff, csr_off);
    k_fillproj<<<dim3(PROJ_BLOCKS + FILL_BLOCKS), dim3(512), 0, stream>>>(
        x, WpT, a_l, a_r, zb, el, er, es, ed, rank, csr_off, csr_src);
    k_node<<<dim3(N_NODES / 8), dim3(256), 0, stream>>>(csr_off, csr_src, el, er, zb, x,
                                                        gamma, beta, lnbuf, out);
    k_ffn<<<dim3(FFN_GRID), dim3(256), 0, stream>>>(W1T, b1, W2T, b2, lnbuf, out);
}

// Round 14
// 153.515 us; speedup vs baseline: 1.9643x; 1.0045x over previous
//
#include <hip/hip_runtime.h>
#include <math.h>

#define N_NODES 50000
#define E_EDGES 800000
#define D_DIM   128
#define H_HEADS 8
#define DH_DIM  16
#define DFF     512

#define SCAN_BLOCKS 98  // 98*512 = 50176 >= N_NODES+1
#define FFN_GRID 256
#define NTILES 3125     // 50000 / 16 exactly
#define PROJ_BLOCKS 782 // ceil(50000/64)
#define FILL_BLOCKS 782 // ceil(800000/1024)

typedef __bf16 bf16_t;
typedef bf16_t bf16x8 __attribute__((ext_vector_type(8)));
typedef float f32x4 __attribute__((ext_vector_type(4)));
typedef unsigned short u16x8 __attribute__((ext_vector_type(8)));

#define SWZ(r) (((r) & 7) << 4)

__device__ __forceinline__ float lrelu(float v) { return v > 0.f ? v : 0.01f * v; }
__device__ __forceinline__ float elu(float v) { return v > 0.f ? v : __expf(v) - 1.f; }
__device__ __forceinline__ unsigned short f2b(float f) {
    unsigned u = __float_as_uint(f);
    unsigned r = (u + 0x7FFFu + ((u >> 16) & 1u)) >> 16;
    return (unsigned short)r;
}

// ---------------- count in-degree + capture rank ----------------
__global__ void k_count(const int* __restrict__ ed, int* __restrict__ counts,
                        int* __restrict__ rank) {
    int e = blockIdx.x * 256 + threadIdx.x;
    if (e < E_EDGES) rank[e] = atomicAdd(&counts[ed[e]], 1);
}

// ---------------- hierarchical scan ----------------
__global__ __launch_bounds__(512) void k_scan1(const int* __restrict__ counts,
                                               int* __restrict__ bsum) {
    int i = blockIdx.x * 512 + threadIdx.x;
    int v = (i < N_NODES) ? counts[i] : 0;
    #pragma unroll
    for (int o = 1; o < 64; o <<= 1) v += __shfl_xor(v, o);
    __shared__ int ws[8];
    if ((threadIdx.x & 63) == 0) ws[threadIdx.x >> 6] = v;
    __syncthreads();
    if (threadIdx.x == 0) {
        int s = 0;
        #pragma unroll
        for (int k = 0; k < 8; ++k) s += ws[k];
        bsum[blockIdx.x] = s;
    }
}

__global__ __launch_bounds__(128) void k_scan2(const int* __restrict__ bsum,
                                               int* __restrict__ boff) {
    __shared__ int tmp[128];
    int t = threadIdx.x;
    int v = (t < SCAN_BLOCKS) ? bsum[t] : 0;
    tmp[t] = v;
    __syncthreads();
    for (int o = 1; o < 128; o <<= 1) {
        int u = (t >= o) ? tmp[t - o] : 0;
        __syncthreads();
        tmp[t] += u;
        __syncthreads();
    }
    boff[t] = (t == 0) ? 0 : tmp[t - 1];
}

__global__ __launch_bounds__(512) void k_scan3(const int* __restrict__ counts,
                                               const int* __restrict__ boff,
                                               int* __restrict__ csr_off) {
    int t = threadIdx.x;
    int i = blockIdx.x * 512 + t;
    int v = (i < N_NODES) ? counts[i] : 0;
    int lane = t & 63, w = t >> 6;
    int xs = v;
    #pragma unroll
    for (int o = 1; o < 64; o <<= 1) {
        int u = __shfl_up(xs, o);
        if (lane >= o) xs += u;
    }
    __shared__ int ws[8];
    __shared__ int wo[8];
    if (lane == 63) ws[w] = xs;
    __syncthreads();
    if (t == 0) {
        int s = 0;
        #pragma unroll
        for (int k = 0; k < 8; ++k) { wo[k] = s; s += ws[k]; }
    }
    __syncthreads();
    int excl = xs - v + wo[w] + boff[blockIdx.x];
    if (i < N_NODES) csr_off[i] = excl;
    if (i == N_NODES) csr_off[N_NODES] = E_EDGES;
}

// ---------------- weight prep: transpose + bf16 (+ fused counts zero) -------
__global__ void k_prep(const float* __restrict__ W1, const float* __restrict__ W2,
                       const float* __restrict__ Wfc,
                       bf16_t* __restrict__ W1T, bf16_t* __restrict__ W2T,
                       bf16_t* __restrict__ WpT, int* __restrict__ counts) {
    int id = blockIdx.x * 256 + threadIdx.x;
    if (id < N_NODES) counts[id] = 0;
    if (id < 512 * 128) {
        int c = id >> 7, k = id & 127;
        W1T[id] = (bf16_t)W1[(size_t)k * 512 + c];
        int c2 = id >> 9, k2 = id & 511;
        W2T[id] = (bf16_t)W2[(size_t)k2 * 128 + c2];
        if (id < 128 * 128) {
            int cp = id >> 7, kp = id & 127;
            WpT[id] = (bf16_t)Wfc[(cp >> 4) * 2048 + kp * 16 + (cp & 15)];
        }
    }
}

// ---------------- FUSED: proj (MFMA) blocks || CSR-fill (scatter) blocks ----
__global__ __launch_bounds__(512) void k_fillproj(const float* __restrict__ x,
                                                  const bf16_t* __restrict__ WpT,
                                                  const float* __restrict__ a_l,
                                                  const float* __restrict__ a_r,
                                                  unsigned short* __restrict__ zb,
                                                  float* __restrict__ el,
                                                  float* __restrict__ er,
                                                  const int* __restrict__ es,
                                                  const int* __restrict__ ed,
                                                  const int* __restrict__ rank,
                                                  const int* __restrict__ csr_off,
                                                  int* __restrict__ csr_src) {
    __shared__ char xbA[16384];  // bf16[64][128], row stride 256B, swizzled
    int t = threadIdx.x;

    if (blockIdx.x >= PROJ_BLOCKS) {
        // ---- fill branch: 1024 edges/block, no atomics ----
        int e0 = (blockIdx.x - PROJ_BLOCKS) * 1024 + t;
        #pragma unroll
        for (int k = 0; k < 2; ++k) {
            int e = e0 + k * 512;
            if (e < E_EDGES) {
                int d = ed[e];
                csr_src[csr_off[d] + rank[e]] = es[e];
            }
        }
        return;
    }

    // ---- proj branch ----
    int r0 = blockIdx.x * 64;
    {
        int r = t >> 3, c0 = (t & 7) * 16;
        int gr = r0 + r;
        u16x8 pk0, pk1;
        if (gr < N_NODES) {
            #pragma unroll
            for (int q = 0; q < 2; ++q) {
                float4 a4 = *(const float4*)&x[(size_t)gr * 128 + c0 + q * 8];
                float4 b4 = *(const float4*)&x[(size_t)gr * 128 + c0 + q * 8 + 4];
                u16x8 pk;
                pk[0] = f2b(a4.x); pk[1] = f2b(a4.y); pk[2] = f2b(a4.z); pk[3] = f2b(a4.w);
                pk[4] = f2b(b4.x); pk[5] = f2b(b4.y); pk[6] = f2b(b4.z); pk[7] = f2b(b4.w);
                if (q == 0) pk0 = pk; else pk1 = pk;
            }
        } else {
            #pragma unroll
            for (int i = 0; i < 8; ++i) { pk0[i] = 0; pk1[i] = 0; }
        }
        int base = r * 256 + c0 * 2;
        *(u16x8*)(xbA + (base ^ SWZ(r))) = pk0;
        *(u16x8*)(xbA + ((base + 16) ^ SWZ(r))) = pk1;
    }
    __syncthreads();

    int wv = t >> 6, l = t & 63;
    int lr = l & 15, lg = l >> 4;

    f32x4 acc[4] = {};
    #pragma unroll
    for (int ks = 0; ks < 4; ++ks) {
        bf16x8 b = *(const bf16x8*)(WpT + (wv * 16 + lr) * 128 + ks * 32 + lg * 8);
        #pragma unroll
        for (int mi = 0; mi < 4; ++mi) {
            int row = mi * 16 + lr;
            int off = (row * 256 + ks * 64 + lg * 16) ^ SWZ(row);
            bf16x8 a = *(const bf16x8*)(xbA + off);
            acc[mi] = __builtin_amdgcn_mfma_f32_16x16x32_bf16(a, b, acc[mi], 0, 0, 0);
        }
    }

    float alv = a_l[wv * 16 + lr];
    float arv = a_r[wv * 16 + lr];
    float outL = 0.f, outR = 0.f;
    #pragma unroll
    for (int mi = 0; mi < 4; ++mi) {
        #pragma unroll
        for (int rg = 0; rg < 4; ++rg) {
            int row = mi * 16 + lg * 4 + rg;
            int grr = r0 + row;
            float v = acc[mi][rg];
            if (grr < N_NODES) zb[(size_t)grr * 128 + wv * 16 + lr] = f2b(v);
            float pl = v * alv, pr = v * arv;
            pl += __shfl_xor(pl, 1); pr += __shfl_xor(pr, 1);
            pl += __shfl_xor(pl, 2); pr += __shfl_xor(pr, 2);
            pl += __shfl_xor(pl, 4); pr += __shfl_xor(pr, 4);
            pl += __shfl_xor(pl, 8); pr += __shfl_xor(pr, 8);
            if (lr == mi * 4 + rg) { outL = pl; outR = pr; }
        }
    }
    int myrow = r0 + (lr >> 2) * 16 + lg * 4 + (lr & 3);
    if (myrow < N_NODES) {
        el[myrow * 8 + wv] = outL;
        er[myrow * 8 + wv] = outR;
    }
}

// ---------------- fused softmax + aggregate + elu + residual + LN -----------
// SINGLE PASS: no max subtraction (e = lrelu(el+er) is bounded ~|e|<3, and
// softmax(e) == softmax(e-m) exactly). Per chunk: clamped index load ->
// el load -> exp -> shuffle -> gather -> fma, chunks independent for MLP.
__global__ __launch_bounds__(256) void k_node(const int* __restrict__ csr_off,
                                              const int* __restrict__ csr_src,
                                              const float* __restrict__ el,
                                              const float* __restrict__ er,
                                              const unsigned short* __restrict__ zb,
                                              const float* __restrict__ x,
                                              const float* __restrict__ gamma,
                                              const float* __restrict__ beta,
                                              unsigned short* __restrict__ lnb,
                                              float* __restrict__ out) {
    int n = blockIdx.x * 8 + (threadIdx.x >> 5);
    int lane = threadIdx.x & 63;
    int q = lane & 31;
    int base = lane & 32;       // shuffle base of this half-wave
    int h = q >> 2, s = q & 3;
    int row = csr_off[n];
    int deg = csr_off[n + 1] - row;
    float4 xv = *(const float4*)&x[(size_t)n * 128 + q * 4];
    float erv = er[n * 8 + h];
    int nch = (deg + 3) >> 2;

    float ps = 0.f;
    float ac0 = 0.f, ac1 = 0.f, ac2 = 0.f, ac3 = 0.f;
    const unsigned short* zbl = zb + q * 4;
    #pragma unroll
    for (int c = 0; c < 8; ++c) {
        if (c * 4 < deg) {  // uniform across half-wave
            int k = c * 4 + s;
            int kk = min(k, deg - 1);          // branch-free clamp
            int src = csr_src[row + kk];
            float e = lrelu(el[src * 8 + h] + erv);
            float p = (k < deg) ? __expf(e) : 0.f;
            ps += p;
            float a[4];
            int se[4];
            #pragma unroll
            for (int tt = 0; tt < 4; ++tt) {
                a[tt] = __shfl(p, base + h * 4 + tt);
                se[tt] = __shfl(src, base + tt);
            }
            uint2 u[4];
            #pragma unroll
            for (int tt = 0; tt < 4; ++tt)
                u[tt] = *(const uint2*)(zbl + (size_t)se[tt] * 128);
            #pragma unroll
            for (int tt = 0; tt < 4; ++tt) {
                ac0 += a[tt] * __uint_as_float(u[tt].x << 16);
                ac1 += a[tt] * __uint_as_float(u[tt].x & 0xFFFF0000u);
                ac2 += a[tt] * __uint_as_float(u[tt].y << 16);
                ac3 += a[tt] * __uint_as_float(u[tt].y & 0xFFFF0000u);
            }
        }
    }
    for (int c = 8; c < nch; ++c) {  // rare: deg > 32
        int k = c * 4 + s;
        int kk = min(k, deg - 1);
        int src = csr_src[row + kk];
        float e = lrelu(el[src * 8 + h] + erv);
        float p = (k < deg) ? __expf(e) : 0.f;
        ps += p;
        float a[4];
        int se[4];
        #pragma unroll
        for (int tt = 0; tt < 4; ++tt) {
            a[tt] = __shfl(p, base + h * 4 + tt);
            se[tt] = __shfl(src, base + tt);
        }
        uint2 u[4];
        #pragma unroll
        for (int tt = 0; tt < 4; ++tt)
            u[tt] = *(const uint2*)(zbl + (size_t)se[tt] * 128);
        #pragma unroll
        for (int tt = 0; tt < 4; ++tt) {
            ac0 += a[tt] * __uint_as_float(u[tt].x << 16);
            ac1 += a[tt] * __uint_as_float(u[tt].x & 0xFFFF0000u);
            ac2 += a[tt] * __uint_as_float(u[tt].y << 16);
            ac3 += a[tt] * __uint_as_float(u[tt].y & 0xFFFF0000u);
        }
    }
    ps += __shfl_xor(ps, 1);
    ps += __shfl_xor(ps, 2);
    float inv = 1.f / fmaxf(ps, 1e-9f);
    float4 hv;
    hv.x = xv.x + elu(ac0 * inv);
    hv.y = xv.y + elu(ac1 * inv);
    hv.z = xv.z + elu(ac2 * inv);
    hv.w = xv.w + elu(ac3 * inv);
    *(float4*)&out[(size_t)n * 128 + q * 4] = hv;

    // LayerNorm over the 128 dims held by this half-wave (32 lanes x 4)
    float rsm = hv.x + hv.y + hv.z + hv.w;
    float rsq = hv.x * hv.x + hv.y * hv.y + hv.z * hv.z + hv.w * hv.w;
    #pragma unroll
    for (int o = 1; o <= 16; o <<= 1) {
        rsm += __shfl_xor(rsm, o);
        rsq += __shfl_xor(rsq, o);
    }
    float mu = rsm * (1.f / 128.f);
    float rs = rsqrtf(rsq * (1.f / 128.f) - mu * mu + 1e-5f);
    float4 g4 = *(const float4*)&gamma[q * 4];
    float4 be4 = *(const float4*)&beta[q * 4];
    ushort4 pk;
    pk.x = f2b((hv.x - mu) * rs * g4.x + be4.x);
    pk.y = f2b((hv.y - mu) * rs * g4.y + be4.y);
    pk.z = f2b((hv.z - mu) * rs * g4.z + be4.z);
    pk.w = f2b((hv.w - mu) * rs * g4.w + be4.w);
    *(ushort4*)&lnb[(size_t)n * 128 + q * 4] = pk;
}

// ---------------- FFN: weight-stationary persistent kernel -----------------
__global__ __launch_bounds__(256, 1) void k_ffn(const bf16_t* __restrict__ W1T,
                                                const float* __restrict__ b1,
                                                const bf16_t* __restrict__ W2T,
                                                const float* __restrict__ b2,
                                                const unsigned short* __restrict__ lnb,
                                                float* __restrict__ out) {
    __shared__ char inA[16384];  // bf16[16 nodes][512 f], row 1024B, swz by node
    int t = threadIdx.x;
    int w = t >> 6, l = t & 63;
    int lr = l & 15, lg = l >> 4;

    bf16x8 w1f[4][8];
    #pragma unroll
    for (int ks = 0; ks < 4; ++ks)
        #pragma unroll
        for (int tf = 0; tf < 8; ++tf)
            w1f[ks][tf] = *(const bf16x8*)(W1T + (size_t)(w * 128 + tf * 16 + lr) * 128 + ks * 32 + lg * 8);
    bf16x8 w2f[16][2];
    #pragma unroll
    for (int ks2 = 0; ks2 < 16; ++ks2)
        #pragma unroll
        for (int tc = 0; tc < 2; ++tc)
            w2f[ks2][tc] = *(const bf16x8*)(W2T + (size_t)(w * 32 + tc * 16 + lr) * 512 + ks2 * 32 + lg * 8);
    float4 b1v[8];
    #pragma unroll
    for (int tf = 0; tf < 8; ++tf)
        b1v[tf] = *(const float4*)&b1[w * 128 + tf * 16 + lg * 4];
    float4 b2v[2];
    #pragma unroll
    for (int tc = 0; tc < 2; ++tc)
        b2v[tc] = *(const float4*)&b2[w * 32 + tc * 16 + lg * 4];

    int tile = blockIdx.x;
    bf16x8 cur[4];
    #pragma unroll
    for (int ks = 0; ks < 4; ++ks)
        cur[ks] = *(const bf16x8*)(lnb + (size_t)(tile * 16 + lr) * 128 + ks * 32 + lg * 8);

    while (tile < NTILES) {
        float4 h4[2];
        #pragma unroll
        for (int tc = 0; tc < 2; ++tc)
            h4[tc] = *(const float4*)(out + (size_t)(tile * 16 + lr) * 128 + w * 32 + tc * 16 + lg * 4);

        f32x4 p[8] = {};
        #pragma unroll
        for (int ks = 0; ks < 4; ++ks)
            #pragma unroll
            for (int tf = 0; tf < 8; ++tf)
                p[tf] = __builtin_amdgcn_mfma_f32_16x16x32_bf16(w1f[ks][tf], cur[ks], p[tf], 0, 0, 0);

        int tn = tile + FFN_GRID;
        if (tn < NTILES) {
            #pragma unroll
            for (int ks = 0; ks < 4; ++ks)
                cur[ks] = *(const bf16x8*)(lnb + (size_t)(tn * 16 + lr) * 128 + ks * 32 + lg * 8);
        }

        #pragma unroll
        for (int tf = 0; tf < 8; ++tf) {
            float4 bb = b1v[tf];
            ushort4 pk;
            float v0 = p[tf][0] + bb.x; pk.x = f2b(v0 > 0.f ? v0 : 0.f);
            float v1 = p[tf][1] + bb.y; pk.y = f2b(v1 > 0.f ? v1 : 0.f);
            float v2 = p[tf][2] + bb.z; pk.z = f2b(v2 > 0.f ? v2 : 0.f);
            float v3 = p[tf][3] + bb.w; pk.w = f2b(v3 > 0.f ? v3 : 0.f);
            *(ushort4*)(inA + ((lr * 1024 + w * 256 + tf * 32 + lg * 8) ^ SWZ(lr))) = pk;
        }
        __syncthreads();

        f32x4 Q[2] = {};
        #pragma unroll
        for (int ks2 = 0; ks2 < 16; ++ks2) {
            bf16x8 bfr = *(const bf16x8*)(inA + ((lr * 1024 + ks2 * 64 + lg * 16) ^ SWZ(lr)));
            #pragma unroll
            for (int tc = 0; tc < 2; ++tc)
                Q[tc] = __builtin_amdgcn_mfma_f32_16x16x32_bf16(w2f[ks2][tc], bfr, Q[tc], 0, 0, 0);
        }

        #pragma unroll
        for (int tc = 0; tc < 2; ++tc) {
            float4 o4;
            o4.x = Q[tc][0] + b2v[tc].x + h4[tc].x;
            o4.y = Q[tc][1] + b2v[tc].y + h4[tc].y;
            o4.z = Q[tc][2] + b2v[tc].z + h4[tc].z;
            o4.w = Q[tc][3] + b2v[tc].w + h4[tc].w;
            *(float4*)(out + (size_t)(tile * 16 + lr) * 128 + w * 32 + tc * 16 + lg * 4) = o4;
        }
        __syncthreads();
        tile = tn;
    }
}

extern "C" void kernel_launch(void* const* d_in, const int* in_sizes, int n_in,
                              void* d_out, int out_size, void* d_ws, size_t ws_size,
                              hipStream_t stream) {
    const float* x     = (const float*)d_in[0];
    const float* Wfc   = (const float*)d_in[1];
    const float* a_l   = (const float*)d_in[2];
    const float* a_r   = (const float*)d_in[3];
    const float* gamma = (const float*)d_in[4];
    const float* beta  = (const float*)d_in[5];
    const float* W1    = (const float*)d_in[6];
    const float* b1    = (const float*)d_in[7];
    const float* W2    = (const float*)d_in[8];
    const float* b2    = (const float*)d_in[9];
    const int*   es    = (const int*)d_in[10];
    const int*   ed    = (const int*)d_in[11];
    float* out = (float*)d_out;

    bf16_t* W1T = (bf16_t*)d_ws;                      // 512*128
    bf16_t* W2T = W1T + 512 * 128;                    // 128*512
    bf16_t* WpT = W2T + 128 * 512;                    // 128*128
    unsigned short* zb = (unsigned short*)(WpT + 128 * 128);  // N*128 bf16
    float* el = (float*)(zb + (size_t)N_NODES * 128); // N*8
    float* er = el + N_NODES * 8;                     // N*8
    int* counts  = (int*)(er + N_NODES * 8);          // N
    int* csr_off = counts + N_NODES;                  // N+1
    int* csr_src = csr_off + N_NODES + 1;             // E
    int* rank    = csr_src + E_EDGES;                 // E
    int* bsum    = rank + E_EDGES;                    // 128
    int* boff    = bsum + 128;                        // 128
    unsigned short* lnbuf = (unsigned short*)(boff + 128);  // N*128 bf16

    k_prep<<<dim3(256), dim3(256), 0, stream>>>(W1, W2, Wfc, W1T, W2T, WpT, counts);
    k_count<<<dim3((E_EDGES + 255) / 256), dim3(256), 0, stream>>>(ed, counts, rank);
    k_scan1<<<dim3(SCAN_BLOCKS), dim3(512), 0, stream>>>(counts, bsum);
    k_scan2<<<dim3(1), dim3(128), 0, stream>>>(bsum, boff);
    k_scan3<<<dim3(SCAN_BLOCKS), dim3(512), 0, stream>>>(counts, boff, csr_off);
    k_fillproj<<<dim3(PROJ_BLOCKS + FILL_BLOCKS), dim3(512), 0, stream>>>(
        x, WpT, a_l, a_r, zb, el, er, es, ed, rank, csr_off, csr_src);
    k_node<<<dim3(N_NODES / 8), dim3(256), 0, stream>>>(csr_off, csr_src, el, er, zb, x,
                                                        gamma, beta, lnbuf, out);
    k_ffn<<<dim3(FFN_GRID), dim3(256), 0, stream>>>(W1T, b1, W2T, b2, lnbuf, out);
}